// Round 9
// baseline (530.820 us; speedup 1.0000x reference)
//
#include <hip/hip_runtime.h>
#include <hip/hip_fp16.h>
#include <cstdint>
#include <cstddef>

#define HH 512
#define WW 512
#define PLANE_H2 (512 * 512 * 16)     // half2 elements per transposed plane
#define PLANE_BYTES (1 << 24)         // 512*512*64B (fp16 plane)
#define NTILE (3 * 512 * 8)           // plane-transpose tile units
#define NBKT 4096                     // 12-bit Morton buckets (32px cubes)

typedef _Float16 f16x8 __attribute__((ext_vector_type(8)));
typedef float    f32x4 __attribute__((ext_vector_type(4)));

// 12-bit interleaved Morton key; top bits x3y3z3 -> contiguous range = octant
__device__ __forceinline__ int key_of(float x, float y, float z) {
    int qx = min(max((int)((x + 1.0f) * 255.5f), 0), 511) >> 5;  // 0..15
    int qy = min(max((int)((y + 1.0f) * 255.5f), 0), 511) >> 5;
    int qz = min(max((int)((z + 1.0f) * 255.5f), 0), 511) >> 5;
    int k = 0;
#pragma unroll
    for (int b = 0; b < 4; ++b) {
        k |= ((qx >> b) & 1) << (3 * b + 2);
        k |= ((qy >> b) & 1) << (3 * b + 1);
        k |= ((qz >> b) & 1) << (3 * b + 0);
    }
    return k;
}

// sorted-coords fetch for group g (clamped)
__device__ __forceinline__ float4 ldco(const float4* __restrict__ sc,
                                       int g, int pl15, int P, int nG) {
    int gg = min(g, nG - 1);
    int pc = min((gg << 4) + pl15, P - 1);
    return sc[pc];
}

// issue one group's 12 corner loads (3 planes x 4 corners, 16B each)
__device__ __forceinline__ void issue_slot(const char* __restrict__ trb,
                                           float4 cc, int kb,
                                           float* wx, float* wy, f16x8* q) {
    float cx = cc.x, cy = cc.y, cz = cc.z;
#pragma unroll
    for (int pl = 0; pl < 3; ++pl) {
        float u = (pl == 1) ? cy : cx;     // -> W axis
        float v = (pl == 0) ? cy : cz;     // -> H axis
        float xf = (u + 1.0f) * (0.5f * 511.0f);
        float yf = (v + 1.0f) * (0.5f * 511.0f);
        float x0f = floorf(xf), y0f = floorf(yf);
        wx[pl] = xf - x0f;
        wy[pl] = yf - y0f;
        int x0 = min(max((int)x0f, 0), 510);
        int y0 = min(max((int)y0f, 0), 510);
        const char* bp = trb + ((size_t)pl * PLANE_BYTES) +
                         ((size_t)(y0 * WW + x0) * 64 + kb * 16);
        q[pl * 4 + 0] = *(const f16x8*)(bp);
        q[pl * 4 + 1] = *(const f16x8*)(bp + 64);
        q[pl * 4 + 2] = *(const f16x8*)(bp + WW * 64);
        q[pl * 4 + 3] = *(const f16x8*)(bp + WW * 64 + 64);
    }
}

// bilinear + product + MFMA MLP + permuted scalar stores (idx from cc.w)
__device__ __forceinline__ void compute_store(
    const f16x8* q, const float* wx, const float* wy, float ccw,
    const _Float16* __restrict__ W1h,   // LDS [128][40]
    const float* b1r, const float* w2r, float b2v,
    float* __restrict__ out, int kb, int pl15) {
    float s[8];
#pragma unroll
    for (int pl = 0; pl < 3; ++pl) {
        float w11 = wx[pl] * wy[pl];
        float w01 = wx[pl] - w11;          // wx*(1-wy)
        float w10 = wy[pl] - w11;          // (1-wx)*wy
        float w00 = 1.0f - wx[pl] - w10;   // (1-wx)*(1-wy)
#pragma unroll
        for (int e = 0; e < 8; ++e) {
            float smp = (float)q[pl * 4 + 0][e] * w00 + (float)q[pl * 4 + 1][e] * w01 +
                        (float)q[pl * 4 + 2][e] * w10 + (float)q[pl * 4 + 3][e] * w11;
            s[e] = (pl == 0) ? smp : s[e] * smp;
        }
    }
    f16x8 af;
#pragma unroll
    for (int e = 0; e < 8; ++e) af[e] = (_Float16)fmaxf(s[e], 0.0f);

    float sum0 = 0.f, sum1 = 0.f, sum2 = 0.f, sum3 = 0.f;
#pragma unroll
    for (int hf = 0; hf < 2; ++hf) {
        f32x4 a0 = {0.f, 0.f, 0.f, 0.f}, a1 = a0, a2 = a0, a3 = a0;
        int ntb = hf * 4;
        const f16x8* bp0 = (const f16x8*)&W1h[(16 * (ntb + 0) + pl15) * 40 + kb * 8];
        const f16x8* bp1 = (const f16x8*)&W1h[(16 * (ntb + 1) + pl15) * 40 + kb * 8];
        const f16x8* bp2 = (const f16x8*)&W1h[(16 * (ntb + 2) + pl15) * 40 + kb * 8];
        const f16x8* bp3 = (const f16x8*)&W1h[(16 * (ntb + 3) + pl15) * 40 + kb * 8];
        a0 = __builtin_amdgcn_mfma_f32_16x16x32_f16(af, *bp0, a0, 0, 0, 0);
        a1 = __builtin_amdgcn_mfma_f32_16x16x32_f16(af, *bp1, a1, 0, 0, 0);
        a2 = __builtin_amdgcn_mfma_f32_16x16x32_f16(af, *bp2, a2, 0, 0, 0);
        a3 = __builtin_amdgcn_mfma_f32_16x16x32_f16(af, *bp3, a3, 0, 0, 0);
#pragma unroll
        for (int r = 0; r < 4; ++r) {
            float h0 = fmaxf(a0[r] + b1r[ntb + 0], 0.0f);
            float h1 = fmaxf(a1[r] + b1r[ntb + 1], 0.0f);
            float h2 = fmaxf(a2[r] + b1r[ntb + 2], 0.0f);
            float h3 = fmaxf(a3[r] + b1r[ntb + 3], 0.0f);
            float v4 = h0 * w2r[ntb + 0] + h1 * w2r[ntb + 1] +
                       h2 * w2r[ntb + 2] + h3 * w2r[ntb + 3];
            if (r == 0) sum0 += v4;
            else if (r == 1) sum1 += v4;
            else if (r == 2) sum2 += v4;
            else sum3 += v4;
        }
    }
#pragma unroll
    for (int m = 1; m <= 8; m <<= 1) {
        sum0 += __shfl_xor(sum0, m, 64);
        sum1 += __shfl_xor(sum1, m, 64);
        sum2 += __shfl_xor(sum2, m, 64);
        sum3 += __shfl_xor(sum3, m, 64);
    }
    // permuted stores: point kb*4+r's idx lives in lane (kb<<4)+(kb*4+r)
    int sb = (kb << 4) + kb * 4;
    int i0 = __float_as_int(__shfl(ccw, sb + 0, 64));
    int i1 = __float_as_int(__shfl(ccw, sb + 1, 64));
    int i2 = __float_as_int(__shfl(ccw, sb + 2, 64));
    int i3 = __float_as_int(__shfl(ccw, sb + 3, 64));
    if (pl15 == 0) {
        out[i0] = sum0 + b2v;
        out[i1] = sum1 + b2v;
        out[i2] = sum2 + b2v;
        out[i3] = sum3 + b2v;
    }
}

// device-wide barrier (co-resident occupancy-sized grid; timeout escape)
__device__ __forceinline__ void dev_barrier(unsigned int* ctr, int nb, int t) {
    __syncthreads();
    if (t == 0) {
        __threadfence();
        __hip_atomic_fetch_add(ctr, 1u, __ATOMIC_ACQ_REL, __HIP_MEMORY_SCOPE_AGENT);
        long long t0 = wall_clock64();
        while (__hip_atomic_load(ctr, __ATOMIC_ACQUIRE, __HIP_MEMORY_SCOPE_AGENT)
               < (unsigned)nb) {
            __builtin_amdgcn_s_sleep(8);
            if (wall_clock64() - t0 > 50000000LL) break;
        }
        __threadfence();
    }
    __syncthreads();
}

// ---------------------------------------------------------------------------
// Phases: A transpose planes -> fp16 HWC | S1 LDS histogram -> global hist |
// BAR1 | per-block redundant exclusive-scan of hist (LDS) + scatter via
// global atomic cursors (output-deterministic) + W1->LDS | BAR2 |
// XCD-sliced depth-2 pipelined gather + MFMA MLP, stores via original index.
// ---------------------------------------------------------------------------
__global__ __launch_bounds__(256, 3) void kp_main(
    const float* __restrict__ coords,
    const float* __restrict__ p0, const float* __restrict__ p1,
    const float* __restrict__ p2,
    const float* __restrict__ W1, const float* __restrict__ b1,
    const float* __restrict__ W2, const float* __restrict__ b2,
    float* __restrict__ out, int P,
    unsigned int* __restrict__ bar, unsigned int* __restrict__ hist,
    unsigned int* __restrict__ cur, float4* __restrict__ sc,
    __half2* __restrict__ tr)
{
    __shared__ __align__(16) char smem[16384];   // union: tileF | ihist | W1h
    float    (*tileF)[65] = (float(*)[65])smem;  // 8320 B (phase A)
    int*      ihist       = (int*)smem;          // 4096 ints (S1/scan/scatter)
    _Float16* W1h         = (_Float16*)smem;     // [128][40] (gather)
    __shared__ int spart[256];
    int t  = threadIdx.x;
    int nb = gridDim.x;

    // ---- phase A: planes [C,H,W] fp32 -> [H,W,C] fp16, grid-stride
    for (int bid = blockIdx.x; bid < NTILE; bid += nb) {
        int xb = bid & 7, y = (bid >> 3) & 511, pl = bid >> 12;
        const float* src = (pl == 0) ? p0 : ((pl == 1) ? p1 : p2);
        int xbase = xb * 64;
        __syncthreads();                       // tile reuse across iters
        int x = t & 63, cq = t >> 6;
#pragma unroll
        for (int i = 0; i < 8; ++i) {
            int c = cq * 8 + i;
            tileF[c][x] = src[c * (HH * WW) + y * WW + xbase + x];
        }
        __syncthreads();
        int c2 = t & 15, xq = t >> 4;
        __half2* dst = tr + (size_t)pl * PLANE_H2 + ((size_t)y * WW + xbase) * 16;
#pragma unroll
        for (int i = 0; i < 4; ++i) {
            int xx = xq * 4 + i;
            dst[xx * 16 + c2] =
                __floats2half2_rn(tileF[2 * c2][xx], tileF[2 * c2 + 1][xx]);
        }
    }
    __syncthreads();   // tileF dead

    // ---- S1: per-block LDS histogram -> global hist
    for (int e = t; e < NBKT; e += 256) ihist[e] = 0;
    __syncthreads();
    int nCh = (P + 255) >> 8;
    for (int ch = blockIdx.x; ch < nCh; ch += nb) {
        int i = (ch << 8) + t;
        if (i < P) {
            float x = coords[3 * i], y = coords[3 * i + 1], z = coords[3 * i + 2];
            atomicAdd(&ihist[key_of(x, y, z)], 1);
        }
    }
    __syncthreads();
    for (int e = t; e < NBKT; e += 256)
        if (ihist[e]) atomicAdd(&hist[e], (unsigned)ihist[e]);

    dev_barrier(&bar[0], nb, t);     // hist + tr complete

    // ---- per-block redundant exclusive scan: ihist = exclusive_prefix(hist)
    {
        int acc = 0;
#pragma unroll
        for (int k = 0; k < 16; ++k) {
            int h = (int)hist[t * 16 + k];
            ihist[t * 16 + k] = h;      // stash raw
            acc += h;
        }
        spart[t] = acc;
        __syncthreads();
        for (int off = 1; off < 256; off <<= 1) {
            int v = (t >= off) ? spart[t - off] : 0;
            __syncthreads();
            spart[t] += v;
            __syncthreads();
        }
        int run = (t > 0) ? spart[t - 1] : 0;
#pragma unroll
        for (int k = 0; k < 16; ++k) {
            int h = ihist[t * 16 + k];
            ihist[t * 16 + k] = run;    // exclusive base
            run += h;
        }
    }
    __syncthreads();

    // ---- scatter via global atomic cursors (slot order nondeterministic;
    //      out[] stays bitwise deterministic: value depends only on point i)
    for (int ch = blockIdx.x; ch < nCh; ch += nb) {
        int i = (ch << 8) + t;
        if (i < P) {
            float x = coords[3 * i], y = coords[3 * i + 1], z = coords[3 * i + 2];
            int key  = key_of(x, y, z);
            int slot = ihist[key] + (int)atomicAdd(&cur[key], 1u);
            float4 v = {x, y, z, __int_as_float(i)};
            sc[slot] = v;
        }
    }
    __syncthreads();   // ihist dead

    // ---- W1 -> LDS fp16 [128][40]
    for (int e = t; e < 4096; e += 256) {
        int j = e >> 5, k = e & 31;
        W1h[j * 40 + k] = (_Float16)W1[k * 128 + j];
    }

    dev_barrier(&bar[16], nb, t);    // sc complete

    // ---- gather + MLP: XCD-sliced, depth-2 pipelined, barrier-free
    int wave = t >> 6, lane = t & 63;
    int pl15 = lane & 15;              // point-in-group / j-lane / D-col
    int kb   = lane >> 4;              // k-block / D-row group
    const char* trb = (const char*)tr;

    float b1r[8], w2r[8];
#pragma unroll
    for (int nt = 0; nt < 8; ++nt) {
        b1r[nt] = b1[16 * nt + pl15];
        w2r[nt] = W2[16 * nt + pl15];
    }
    float b2v = b2[0];

    int nG  = (P + 15) >> 4;
    int xcd = blockIdx.x & 7;
    int lb  = blockIdx.x >> 3;
    int nbs = (nb >> 3) + ((blockIdx.x & 7) < (nb & 7) ? 1 : 0);
    int gs  = (int)(((long long)xcd * nG) >> 3);
    int ge  = (int)(((long long)(xcd + 1) * nG) >> 3);
    int nws = nbs * 4;

    float wxA[3], wyA[3], wxB[3], wyB[3];
    f16x8 qA[12], qB[12];

    int g = gs + lb * 4 + wave;
    if (g < ge) {
        float4 cc0 = ldco(sc, g, pl15, P, nG);
        float4 cc1 = ldco(sc, g + nws, pl15, P, nG);
        issue_slot(trb, cc0, kb, wxA, wyA, qA);
        float cwA = cc0.w, cwB;
        while (true) {
            issue_slot(trb, cc1, kb, wxB, wyB, qB);
            cwB = cc1.w;
            cc0 = ldco(sc, g + 2 * nws, pl15, P, nG);
            compute_store(qA, wxA, wyA, cwA, W1h, b1r, w2r, b2v, out, kb, pl15);
            g += nws;
            if (g >= ge) break;

            issue_slot(trb, cc0, kb, wxA, wyA, qA);
            cwA = cc0.w;
            cc1 = ldco(sc, g + 2 * nws, pl15, P, nG);
            compute_store(qB, wxB, wyB, cwB, W1h, b1r, w2r, b2v, out, kb, pl15);
            g += nws;
            if (g >= ge) break;
        }
    }
}

// ---------------------------------------------------------------------------
// Fallback (ws too small): direct CHW fp32 sampling, no workspace.
// ---------------------------------------------------------------------------
__global__ __launch_bounds__(256) void kp_direct(
    const float* __restrict__ coords,
    const float* __restrict__ p0, const float* __restrict__ p1,
    const float* __restrict__ p2,
    const float* __restrict__ W1, const float* __restrict__ b1,
    const float* __restrict__ W2, const float* __restrict__ b2,
    float* __restrict__ out, int P)
{
    __shared__ float feats[256][33];
    int t = threadIdx.x;
    int wave = t >> 6, lane = t & 63, c = lane & 31, xsel = lane >> 5;
    int pbase = blockIdx.x * 256;

    for (int i = 0; i < 64; ++i) {
        int p = pbase + i * 4 + wave;
        if (p < P) {
            float cx = coords[3 * p + 0];
            float cy = coords[3 * p + 1];
            float cz = coords[3 * p + 2];
            float f = 1.0f;
#pragma unroll
            for (int pl = 0; pl < 3; ++pl) {
                const float* plane = (pl == 0) ? p0 : ((pl == 1) ? p1 : p2);
                float u = (pl == 1) ? cy : cx;
                float v = (pl == 0) ? cy : cz;
                float xf = (u + 1.0f) * (0.5f * 511.0f);
                float yf = (v + 1.0f) * (0.5f * 511.0f);
                float x0f = floorf(xf), y0f = floorf(yf);
                float wx = xf - x0f, wy = yf - y0f;
                int x0 = min(max((int)x0f, 0), 510);
                int y0 = min(max((int)y0f, 0), 510);
                const float* bp = plane + (size_t)c * (HH * WW) +
                                  (size_t)y0 * WW + (x0 + xsel);
                float v0 = bp[0];
                float v1 = bp[WW];
                float wxl = xsel ? wx : (1.0f - wx);
                float sm = (v0 * (1.0f - wy) + v1 * wy) * wxl;
                sm += __shfl_xor(sm, 32, 64);
                f *= sm;
            }
            if (xsel == 0) feats[i * 4 + wave][c] = fmaxf(f, 0.0f);
        }
    }
    __syncthreads();
    int p = pbase + t;
    if (p < P) {
        float fr[32];
#pragma unroll
        for (int k = 0; k < 32; ++k) fr[k] = feats[t][k];
        float acc = b2[0];
#pragma unroll 4
        for (int j = 0; j < 128; ++j) {
            float a = b1[j];
#pragma unroll
            for (int k = 0; k < 32; ++k) a += fr[k] * W1[k * 128 + j];
            acc += fmaxf(a, 0.0f) * W2[j];
        }
        out[p] = acc;
    }
}

// ---------------------------------------------------------------------------
extern "C" void kernel_launch(void* const* d_in, const int* in_sizes, int n_in,
                              void* d_out, int out_size, void* d_ws, size_t ws_size,
                              hipStream_t stream) {
    const float* coords = (const float*)d_in[0];
    const float* p0 = (const float*)d_in[1];
    const float* p1 = (const float*)d_in[2];
    const float* p2 = (const float*)d_in[3];
    const float* W1 = (const float*)d_in[4];
    const float* b1 = (const float*)d_in[5];
    const float* W2 = (const float*)d_in[6];
    const float* b2 = (const float*)d_in[7];
    float* out = (float*)d_out;
    int P = in_sizes[0] / 3;   // 2,000,000

    // ws layout: [0..255] barriers | hist 16KB | cur 16KB | sc (P x 16B)
    //            | tr planes (48MB fp16)
    const size_t hist_off = 256;
    const size_t cur_off  = hist_off + NBKT * sizeof(unsigned int);   // 16640
    const size_t sc_off   = (cur_off + NBKT * sizeof(unsigned int) + 255) & ~(size_t)255;
    const size_t tr_off   = (sc_off + (size_t)P * 16 + 255) & ~(size_t)255;
    const size_t need     = tr_off + (size_t)3 * PLANE_BYTES;
    const size_t zero_len = sc_off;   // barriers + hist + cur

    if (ws_size >= need) {
        int dev = 0, nCU = 0, maxb = 0;
        hipGetDevice(&dev);
        hipDeviceGetAttribute(&nCU, hipDeviceAttributeMultiprocessorCount, dev);
        hipOccupancyMaxActiveBlocksPerMultiprocessor(&maxb, kp_main, 256, 0);
        if (nCU <= 0) nCU = 32;
        if (maxb <= 0) maxb = 1;
        int nblk = nCU * maxb;

        unsigned int* bar  = (unsigned int*)d_ws;
        unsigned int* hist = (unsigned int*)((char*)d_ws + hist_off);
        unsigned int* cur  = (unsigned int*)((char*)d_ws + cur_off);
        float4*       sc   = (float4*)((char*)d_ws + sc_off);
        __half2*      tr   = (__half2*)((char*)d_ws + tr_off);
        hipMemsetAsync(d_ws, 0, zero_len, stream);   // barriers + hist + cur
        kp_main<<<dim3(nblk), dim3(256), 0, stream>>>(
            coords, p0, p1, p2, W1, b1, W2, b2, out, P, bar, hist, cur, sc, tr);
    } else {
        int nblk = (P + 255) / 256;
        kp_direct<<<dim3(nblk), dim3(256), 0, stream>>>(
            coords, p0, p1, p2, W1, b1, W2, b2, out, P);
    }
}

// Round 10
// 356.590 us; speedup vs baseline: 1.4886x; 1.4886x over previous
//
#include <hip/hip_runtime.h>
#include <hip/hip_fp16.h>
#include <cstdint>
#include <cstddef>

#define HH 512
#define WW 512
#define PLANE_H2 (512 * 512 * 16)     // half2 elements per transposed plane
#define PLANE_BYTES (1 << 24)         // 512*512*64B (fp16 plane)
#define NTILE (3 * 512 * 8)           // plane-transpose tile units

typedef _Float16 f16x8 __attribute__((ext_vector_type(8)));
typedef float    f32x4 __attribute__((ext_vector_type(4)));

// coords fetch for a 16-pt group (clamped; duplicate tail groups recompute
// identical values -> bitwise-deterministic output)
__device__ __forceinline__ float4 ldco(const float* __restrict__ coords,
                                       int g, int pl15, int P, int nG) {
    int gg = min(g, nG - 1);
    int pc = min((gg << 4) + pl15, P - 1);
    return *(const float4*)(coords + (size_t)pc * 3);
}

// issue one group's 12 corner loads (3 planes x 4 corners, 16B each)
__device__ __forceinline__ void issue_slot(const char* __restrict__ trb,
                                           float4 cc, int kb,
                                           float* wx, float* wy, f16x8* q) {
    float cx = cc.x, cy = cc.y, cz = cc.z;
#pragma unroll
    for (int pl = 0; pl < 3; ++pl) {
        float u = (pl == 1) ? cy : cx;     // -> W axis
        float v = (pl == 0) ? cy : cz;     // -> H axis
        float xf = (u + 1.0f) * (0.5f * 511.0f);
        float yf = (v + 1.0f) * (0.5f * 511.0f);
        float x0f = floorf(xf), y0f = floorf(yf);
        wx[pl] = xf - x0f;
        wy[pl] = yf - y0f;
        int x0 = min(max((int)x0f, 0), 510);
        int y0 = min(max((int)y0f, 0), 510);
        const char* bp = trb + ((size_t)pl * PLANE_BYTES) +
                         ((size_t)(y0 * WW + x0) * 64 + kb * 16);
        q[pl * 4 + 0] = *(const f16x8*)(bp);
        q[pl * 4 + 1] = *(const f16x8*)(bp + 64);
        q[pl * 4 + 2] = *(const f16x8*)(bp + WW * 64);
        q[pl * 4 + 3] = *(const f16x8*)(bp + WW * 64 + 64);
    }
}

// bilinear + product + MFMA MLP + store for one group (validated r5/r6)
__device__ __forceinline__ void compute_store(
    const f16x8* q, const float* wx, const float* wy,
    const _Float16* __restrict__ W1h,   // LDS [128][40]
    const float* b1r, const float* w2r, float b2v,
    float* __restrict__ out, int pbase, int P, int kb, int pl15) {
    float s[8];
#pragma unroll
    for (int pl = 0; pl < 3; ++pl) {
        float w11 = wx[pl] * wy[pl];
        float w01 = wx[pl] - w11;          // wx*(1-wy)
        float w10 = wy[pl] - w11;          // (1-wx)*wy
        float w00 = 1.0f - wx[pl] - w10;   // (1-wx)*(1-wy)
#pragma unroll
        for (int e = 0; e < 8; ++e) {
            float smp = (float)q[pl * 4 + 0][e] * w00 + (float)q[pl * 4 + 1][e] * w01 +
                        (float)q[pl * 4 + 2][e] * w10 + (float)q[pl * 4 + 3][e] * w11;
            s[e] = (pl == 0) ? smp : s[e] * smp;
        }
    }
    f16x8 af;
#pragma unroll
    for (int e = 0; e < 8; ++e) af[e] = (_Float16)fmaxf(s[e], 0.0f);

    float sum0 = 0.f, sum1 = 0.f, sum2 = 0.f, sum3 = 0.f;
#pragma unroll
    for (int hf = 0; hf < 2; ++hf) {
        f32x4 a0 = {0.f, 0.f, 0.f, 0.f}, a1 = a0, a2 = a0, a3 = a0;
        int ntb = hf * 4;
        const f16x8* bp0 = (const f16x8*)&W1h[(16 * (ntb + 0) + pl15) * 40 + kb * 8];
        const f16x8* bp1 = (const f16x8*)&W1h[(16 * (ntb + 1) + pl15) * 40 + kb * 8];
        const f16x8* bp2 = (const f16x8*)&W1h[(16 * (ntb + 2) + pl15) * 40 + kb * 8];
        const f16x8* bp3 = (const f16x8*)&W1h[(16 * (ntb + 3) + pl15) * 40 + kb * 8];
        a0 = __builtin_amdgcn_mfma_f32_16x16x32_f16(af, *bp0, a0, 0, 0, 0);
        a1 = __builtin_amdgcn_mfma_f32_16x16x32_f16(af, *bp1, a1, 0, 0, 0);
        a2 = __builtin_amdgcn_mfma_f32_16x16x32_f16(af, *bp2, a2, 0, 0, 0);
        a3 = __builtin_amdgcn_mfma_f32_16x16x32_f16(af, *bp3, a3, 0, 0, 0);
#pragma unroll
        for (int r = 0; r < 4; ++r) {
            float h0 = fmaxf(a0[r] + b1r[ntb + 0], 0.0f);
            float h1 = fmaxf(a1[r] + b1r[ntb + 1], 0.0f);
            float h2 = fmaxf(a2[r] + b1r[ntb + 2], 0.0f);
            float h3 = fmaxf(a3[r] + b1r[ntb + 3], 0.0f);
            float v4 = h0 * w2r[ntb + 0] + h1 * w2r[ntb + 1] +
                       h2 * w2r[ntb + 2] + h3 * w2r[ntb + 3];
            if (r == 0) sum0 += v4;
            else if (r == 1) sum1 += v4;
            else if (r == 2) sum2 += v4;
            else sum3 += v4;
        }
    }
#pragma unroll
    for (int m = 1; m <= 8; m <<= 1) {
        sum0 += __shfl_xor(sum0, m, 64);
        sum1 += __shfl_xor(sum1, m, 64);
        sum2 += __shfl_xor(sum2, m, 64);
        sum3 += __shfl_xor(sum3, m, 64);
    }
    if (pl15 == 0) {                        // lanes 0,16,32,48 -> rows kb*4..+3
        int op = pbase + kb * 4;
        if (op + 3 < P) {
            float4 o = {sum0 + b2v, sum1 + b2v, sum2 + b2v, sum3 + b2v};
            *(float4*)(out + op) = o;       // pbase%16==0 -> 16B aligned
        } else {
            if (op + 0 < P) out[op + 0] = sum0 + b2v;
            if (op + 1 < P) out[op + 1] = sum1 + b2v;
            if (op + 2 < P) out[op + 2] = sum2 + b2v;
            if (op + 3 < P) out[op + 3] = sum3 + b2v;
        }
    }
}

// ---------------------------------------------------------------------------
// Single-dispatch persistent kernel; phase B is a TRUE depth-3 rotation
// (3 corner slots in flight, coords prefetched one triple ahead) under
// __launch_bounds__(256,2) so all 3 slots stay in registers (no spill).
// No sort (r8/r9 showed bytes are not the binding constraint).
// ---------------------------------------------------------------------------
__global__ __launch_bounds__(256, 2) void kp_main(
    const float* __restrict__ coords,
    const float* __restrict__ p0, const float* __restrict__ p1,
    const float* __restrict__ p2,
    const float* __restrict__ W1, const float* __restrict__ b1,
    const float* __restrict__ W2, const float* __restrict__ b2,
    float* __restrict__ out, int P,
    unsigned int* __restrict__ bar, __half2* __restrict__ tr)
{
    __shared__ __align__(16) char smem[10240];          // union: tileF | W1h
    float    (*tileF)[65] = (float(*)[65])smem;         // 8320 B (phase A only)
    _Float16* W1h         = (_Float16*)smem;            // [128][40] = 10240 B
    int t  = threadIdx.x;
    int nb = gridDim.x;

    // ---- phase A: planes [C,H,W] fp32 -> [H,W,C] fp16, grid-stride
    for (int bid = blockIdx.x; bid < NTILE; bid += nb) {
        int xb = bid & 7, y = (bid >> 3) & 511, pl = bid >> 12;
        const float* src = (pl == 0) ? p0 : ((pl == 1) ? p1 : p2);
        int xbase = xb * 64;
        __syncthreads();                       // tile reuse across iters
        int x = t & 63, cq = t >> 6;
#pragma unroll
        for (int i = 0; i < 8; ++i) {
            int c = cq * 8 + i;
            tileF[c][x] = src[c * (HH * WW) + y * WW + xbase + x];
        }
        __syncthreads();
        int c2 = t & 15, xq = t >> 4;
        __half2* dst = tr + (size_t)pl * PLANE_H2 + ((size_t)y * WW + xbase) * 16;
#pragma unroll
        for (int i = 0; i < 4; ++i) {
            int xx = xq * 4 + i;
            dst[xx * 16 + c2] =
                __floats2half2_rn(tileF[2 * c2][xx], tileF[2 * c2 + 1][xx]);
        }
    }
    __syncthreads();   // all tile reads done before W1h overwrites the union

    // ---- W1 -> LDS fp16 [128][40]
    for (int e = t; e < 4096; e += 256) {
        int j = e >> 5, k = e & 31;
        W1h[j * 40 + k] = (_Float16)W1[k * 128 + j];
    }

    // ---- device-wide barrier (occupancy-sized grid + timeout escape)
    __syncthreads();
    if (t == 0) {
        __threadfence();   // release tr
        __hip_atomic_fetch_add(bar, 1u, __ATOMIC_ACQ_REL, __HIP_MEMORY_SCOPE_AGENT);
        long long t0 = wall_clock64();
        while (__hip_atomic_load(bar, __ATOMIC_ACQUIRE, __HIP_MEMORY_SCOPE_AGENT)
               < (unsigned)nb) {
            __builtin_amdgcn_s_sleep(8);
            if (wall_clock64() - t0 > 50000000LL) break;   // ~0.5 s escape hatch
        }
        __threadfence();   // acquire
    }
    __syncthreads();       // also makes W1h visible block-wide

    // ---- phase B: depth-3 rotated pipeline, barrier-free
    int wave = t >> 6, lane = t & 63;
    int pl15 = lane & 15;              // point-in-group / j-lane / D-col
    int kb   = lane >> 4;              // k-block / D-row group
    const char* trb = (const char*)tr;

    float b1r[8], w2r[8];
#pragma unroll
    for (int nt = 0; nt < 8; ++nt) {
        b1r[nt] = b1[16 * nt + pl15];
        w2r[nt] = W2[16 * nt + pl15];
    }
    float b2v = b2[0];

    int wid = blockIdx.x * 4 + wave;
    int nw  = nb * 4;
    int nG  = (P + 15) >> 4;

    if (wid < nG) {
        float wxA[3], wyA[3], wxB[3], wyB[3], wxC[3], wyC[3];
        f16x8 qA[12], qB[12], qC[12];

        // prologue: slots A,B issued; coords for C and the next triple staged
        float4 cc = ldco(coords, wid, pl15, P, nG);
        issue_slot(trb, cc, kb, wxA, wyA, qA);
        cc = ldco(coords, wid + nw, pl15, P, nG);
        issue_slot(trb, cc, kb, wxB, wyB, qB);
        float4 ccC  = ldco(coords, wid + 2 * nw, pl15, P, nG);
        float4 ccA2 = ldco(coords, wid + 3 * nw, pl15, P, nG);
        float4 ccB2 = ldco(coords, wid + 4 * nw, pl15, P, nG);

        int g = wid;
        while (g < nG) {
            // --- sub-step 1: slot C issues group g+2nw, compute group g (A)
            issue_slot(trb, ccC, kb, wxC, wyC, qC);
            float4 ccC2 = ldco(coords, g + 5 * nw, pl15, P, nG);
            compute_store(qA, wxA, wyA, W1h, b1r, w2r, b2v, out,
                          min(g, nG - 1) << 4, P, kb, pl15);
            // --- sub-step 2: slot A issues group g+3nw, compute g+nw (B)
            issue_slot(trb, ccA2, kb, wxA, wyA, qA);
            float4 ccA3 = ldco(coords, g + 6 * nw, pl15, P, nG);
            compute_store(qB, wxB, wyB, W1h, b1r, w2r, b2v, out,
                          min(g + nw, nG - 1) << 4, P, kb, pl15);
            // --- sub-step 3: slot B issues group g+4nw, compute g+2nw (C)
            issue_slot(trb, ccB2, kb, wxB, wyB, qB);
            float4 ccB3 = ldco(coords, g + 7 * nw, pl15, P, nG);
            compute_store(qC, wxC, wyC, W1h, b1r, w2r, b2v, out,
                          min(g + 2 * nw, nG - 1) << 4, P, kb, pl15);
            ccC = ccC2; ccA2 = ccA3; ccB2 = ccB3;
            g += 3 * nw;
        }
    }
}

// ---------------------------------------------------------------------------
// Fallback (ws too small): direct CHW fp32 sampling, no workspace.
// ---------------------------------------------------------------------------
__global__ __launch_bounds__(256) void kp_direct(
    const float* __restrict__ coords,
    const float* __restrict__ p0, const float* __restrict__ p1,
    const float* __restrict__ p2,
    const float* __restrict__ W1, const float* __restrict__ b1,
    const float* __restrict__ W2, const float* __restrict__ b2,
    float* __restrict__ out, int P)
{
    __shared__ float feats[256][33];
    int t = threadIdx.x;
    int wave = t >> 6, lane = t & 63, c = lane & 31, xsel = lane >> 5;
    int pbase = blockIdx.x * 256;

    for (int i = 0; i < 64; ++i) {
        int p = pbase + i * 4 + wave;
        if (p < P) {
            float cx = coords[3 * p + 0];
            float cy = coords[3 * p + 1];
            float cz = coords[3 * p + 2];
            float f = 1.0f;
#pragma unroll
            for (int pl = 0; pl < 3; ++pl) {
                const float* plane = (pl == 0) ? p0 : ((pl == 1) ? p1 : p2);
                float u = (pl == 1) ? cy : cx;
                float v = (pl == 0) ? cy : cz;
                float xf = (u + 1.0f) * (0.5f * 511.0f);
                float yf = (v + 1.0f) * (0.5f * 511.0f);
                float x0f = floorf(xf), y0f = floorf(yf);
                float wx = xf - x0f, wy = yf - y0f;
                int x0 = min(max((int)x0f, 0), 510);
                int y0 = min(max((int)y0f, 0), 510);
                const float* bp = plane + (size_t)c * (HH * WW) +
                                  (size_t)y0 * WW + (x0 + xsel);
                float v0 = bp[0];
                float v1 = bp[WW];
                float wxl = xsel ? wx : (1.0f - wx);
                float sm = (v0 * (1.0f - wy) + v1 * wy) * wxl;
                sm += __shfl_xor(sm, 32, 64);
                f *= sm;
            }
            if (xsel == 0) feats[i * 4 + wave][c] = fmaxf(f, 0.0f);
        }
    }
    __syncthreads();
    int p = pbase + t;
    if (p < P) {
        float fr[32];
#pragma unroll
        for (int k = 0; k < 32; ++k) fr[k] = feats[t][k];
        float acc = b2[0];
#pragma unroll 4
        for (int j = 0; j < 128; ++j) {
            float a = b1[j];
#pragma unroll
            for (int k = 0; k < 32; ++k) a += fr[k] * W1[k * 128 + j];
            acc += fmaxf(a, 0.0f) * W2[j];
        }
        out[p] = acc;
    }
}

// ---------------------------------------------------------------------------
extern "C" void kernel_launch(void* const* d_in, const int* in_sizes, int n_in,
                              void* d_out, int out_size, void* d_ws, size_t ws_size,
                              hipStream_t stream) {
    const float* coords = (const float*)d_in[0];
    const float* p0 = (const float*)d_in[1];
    const float* p1 = (const float*)d_in[2];
    const float* p2 = (const float*)d_in[3];
    const float* W1 = (const float*)d_in[4];
    const float* b1 = (const float*)d_in[5];
    const float* W2 = (const float*)d_in[6];
    const float* b2 = (const float*)d_in[7];
    float* out = (float*)d_out;
    int P = in_sizes[0] / 3;   // 2,000,000

    // ws layout: [0..511] barrier | tr planes (3 x 16MB fp16)
    const size_t tr_off = 512;
    const size_t need   = tr_off + (size_t)3 * PLANE_BYTES;

    if (ws_size >= need) {
        int dev = 0, nCU = 0, maxb = 0;
        hipGetDevice(&dev);
        hipDeviceGetAttribute(&nCU, hipDeviceAttributeMultiprocessorCount, dev);
        hipOccupancyMaxActiveBlocksPerMultiprocessor(&maxb, kp_main, 256, 0);
        if (nCU <= 0) nCU = 32;
        if (maxb <= 0) maxb = 1;
        int nblk = nCU * maxb;

        unsigned int* bar = (unsigned int*)d_ws;
        __half2* tr = (__half2*)((char*)d_ws + tr_off);
        hipMemsetAsync(d_ws, 0, 512, stream);    // reset barrier counter (in-graph)
        kp_main<<<dim3(nblk), dim3(256), 0, stream>>>(
            coords, p0, p1, p2, W1, b1, W2, b2, out, P, bar, tr);
    } else {
        int nblk = (P + 255) / 256;
        kp_direct<<<dim3(nblk), dim3(256), 0, stream>>>(
            coords, p0, p1, p2, W1, b1, W2, b2, out, P);
    }
}